// Round 1
// baseline (75.301 us; speedup 1.0000x reference)
//
#include <hip/hip_runtime.h>
#include <hip/hip_bf16.h>

typedef __attribute__((ext_vector_type(8))) short bf16x8;
typedef __attribute__((ext_vector_type(4))) float f32x4;

#define N_PTS   16384
#define C_CH    64
#define K_ADJ   17
#define C_OUT   128
#define N_J     16

// bf16 weights, layout [j][o][c] so an A-fragment read is 16B contiguous per lane.
__device__ __hip_bfloat16 g_wb[N_J * C_OUT * C_CH];

__global__ __launch_bounds__(256) void prep_weights_k(const float* __restrict__ w) {
    int idx = blockIdx.x * 256 + threadIdx.x;      // 0 .. 131071 exactly
    int c = idx & 63;
    int o = (idx >> 6) & 127;
    int j = idx >> 13;
    g_wb[idx] = __float2bfloat16(w[(o * C_CH + c) * N_J + j]);
}

// Block: 256 threads = 4 waves. Block tile: 64 tokens x 128 outputs.
// wave wid: tg = wid&1 (32-token group), oh = wid>>1 (64-output half).
// Within a wave: lane l owns token (l&15) of each 16-token subgroup g,
// channels (l>>4)*8 + {0..7} and +32 -> exactly the MFMA B-fragment layout.
__global__ __launch_bounds__(256, 2) void sconv_k(
    const float* __restrict__ x,
    const int*   __restrict__ adj,
    float*       __restrict__ out)
{
    // XCD-aware swizzle (bijective, 512 blocks): first batch -> XCDs 0..3,
    // second batch -> XCDs 4..7, so each XCD's L2 holds one 4 MB x slice.
    const int p      = blockIdx.x;
    const int g8     = p & 7;
    const int b      = g8 >> 2;                     // batch
    const int slot   = ((p >> 3) << 2) | (g8 & 3);  // 0..255 within batch

    const int lane = threadIdx.x & 63;
    const int wid  = threadIdx.x >> 6;
    const int tg   = wid & 1;
    const int oh   = wid >> 1;
    const int lrow = lane & 15;
    const int lk   = lane >> 4;
    const int cb   = lk * 8;

    const int nbase = slot * 64 + tg * 32;

    const float* __restrict__ xb   = x   + (size_t)b * N_PTS * C_CH;
    const int*   __restrict__ adjb = adj + (size_t)b * N_PTS * K_ADJ;
    float*       __restrict__ ob   = out + (size_t)b * C_OUT * N_PTS;

    // center rows (16 channels per lane per token-group)
    int   nidx[2];
    float center[2][16];
    #pragma unroll
    for (int g = 0; g < 2; ++g) {
        const int n = nbase + g * 16 + lrow;
        nidx[g] = n;
        const float* rp = xb + n * C_CH + cb;
        const float4 v0 = *(const float4*)(rp + 0);
        const float4 v1 = *(const float4*)(rp + 4);
        const float4 v2 = *(const float4*)(rp + 32);
        const float4 v3 = *(const float4*)(rp + 36);
        center[g][0]  = v0.x; center[g][1]  = v0.y; center[g][2]  = v0.z; center[g][3]  = v0.w;
        center[g][4]  = v1.x; center[g][5]  = v1.y; center[g][6]  = v1.z; center[g][7]  = v1.w;
        center[g][8]  = v2.x; center[g][9]  = v2.y; center[g][10] = v2.z; center[g][11] = v2.w;
        center[g][12] = v3.x; center[g][13] = v3.y; center[g][14] = v3.z; center[g][15] = v3.w;
    }

    // preload all neighbor indices (removes the adj->row serial chain per j)
    int aidx[2][N_J];
    #pragma unroll
    for (int g = 0; g < 2; ++g) {
        const int base = nidx[g] * K_ADJ + 1;
        #pragma unroll
        for (int j = 0; j < N_J; ++j) aidx[g][j] = adjb[base + j];
    }

    f32x4 maxacc[4][2];
    #pragma unroll
    for (int of = 0; of < 4; ++of)
        #pragma unroll
        for (int g = 0; g < 2; ++g)
            maxacc[of][g] = f32x4{0.f, 0.f, 0.f, 0.f};

    const __hip_bfloat16* __restrict__ wb = g_wb;

    #pragma unroll
    for (int j = 0; j < N_J; ++j) {
        // ---- gather + proj -> B fragments (registers only) ----
        bf16x8 bfrag[2][2];
        #pragma unroll
        for (int g = 0; g < 2; ++g) {
            const float* rp = xb + aidx[g][j] * C_CH + cb;
            const float4 v0 = *(const float4*)(rp + 0);
            const float4 v1 = *(const float4*)(rp + 4);
            const float4 v2 = *(const float4*)(rp + 32);
            const float4 v3 = *(const float4*)(rp + 36);
            float d[16];
            d[0]=v0.x;  d[1]=v0.y;  d[2]=v0.z;  d[3]=v0.w;
            d[4]=v1.x;  d[5]=v1.y;  d[6]=v1.z;  d[7]=v1.w;
            d[8]=v2.x;  d[9]=v2.y;  d[10]=v2.z; d[11]=v2.w;
            d[12]=v3.x; d[13]=v3.y; d[14]=v3.z; d[15]=v3.w;
            float s = 0.f;
            #pragma unroll
            for (int i = 0; i < 16; ++i) { d[i] -= center[g][i]; s = fmaf(d[i], d[i], s); }
            // full 64-ch sum: 4 lanes (l, l^16, l^32, l^48) share one token
            s += __shfl_xor(s, 16);
            s += __shfl_xor(s, 32);
            // frame normalizer: sqrt(sum(diff^2) + norm^2) = sqrt(2)*norm
            const float scale = rsqrtf(2.0f * s);
            #pragma unroll
            for (int i = 0; i < 8; ++i) {
                bfrag[g][0][i] = (short)__builtin_bit_cast(unsigned short, __float2bfloat16(d[i]     * scale));
                bfrag[g][1][i] = (short)__builtin_bit_cast(unsigned short, __float2bfloat16(d[i + 8] * scale));
            }
        }

        // ---- MFMA: D[o_local][t_local] += W_j[o][c] * proj[t][c] ----
        const __hip_bfloat16* wj = wb + j * (C_OUT * C_CH);
        #pragma unroll
        for (int of = 0; of < 4; ++of) {
            const __hip_bfloat16* wr = wj + (oh * 64 + of * 16 + lrow) * C_CH + cb;
            const bf16x8 a0 = *(const bf16x8*)(wr);        // channels cb+0..7
            const bf16x8 a1 = *(const bf16x8*)(wr + 32);   // channels cb+32..39
            #pragma unroll
            for (int g = 0; g < 2; ++g) {
                f32x4 acc = f32x4{0.f, 0.f, 0.f, 0.f};
                acc = __builtin_amdgcn_mfma_f32_16x16x32_bf16(a0, bfrag[g][0], acc, 0, 0, 0);
                acc = __builtin_amdgcn_mfma_f32_16x16x32_bf16(a1, bfrag[g][1], acc, 0, 0, 0);
                #pragma unroll
                for (int r = 0; r < 4; ++r)
                    maxacc[of][g][r] = fmaxf(maxacc[of][g][r], acc[r]); // relu folded: maxacc init 0
            }
        }
    }

    // ---- store: D row = (lane>>4)*4 + r, col = lane&15 (token) ----
    #pragma unroll
    for (int of = 0; of < 4; ++of) {
        const int o0 = oh * 64 + of * 16 + lk * 4;
        #pragma unroll
        for (int g = 0; g < 2; ++g) {
            const int n = nbase + g * 16 + lrow;
            #pragma unroll
            for (int r = 0; r < 4; ++r)
                ob[(o0 + r) * N_PTS + n] = maxacc[of][g][r];
        }
    }
}

extern "C" void kernel_launch(void* const* d_in, const int* in_sizes, int n_in,
                              void* d_out, int out_size, void* d_ws, size_t ws_size,
                              hipStream_t stream) {
    (void)in_sizes; (void)n_in; (void)d_ws; (void)ws_size; (void)out_size;
    const float* x   = (const float*)d_in[0];
    const int*   adj = (const int*)d_in[1];
    const float* w   = (const float*)d_in[2];
    float*       out = (float*)d_out;

    hipLaunchKernelGGL(prep_weights_k, dim3(512), dim3(256), 0, stream, w);
    hipLaunchKernelGGL(sconv_k,        dim3(512), dim3(256), 0, stream, x, adj, out);
}